// Round 10
// baseline (632.362 us; speedup 1.0000x reference)
//
#include <hip/hip_runtime.h>
#include <hip/hip_bf16.h>

// ---------------------------------------------------------------------------
// Causal MHA. B=2, S=2048, D=1024, H=16, Dh=64. Inputs fp32, output fp32.
// Internal bf16 MFMA.
// Memory plan (ws 24 MB, d_out 16 MB):
//   d_out[0:8MB]   Q   (B,H,S,Dh) bf16     d_out[8:16MB]  xb (4096,1024) bf16
//   ws[0:8MB]      K   (B,H,S,Dh) bf16 (dead after attn -> Wo-bf16)
//   ws[8:16MB]     VT  (B,H,Dh,S) bf16
//   ws[16:24MB]    Wq/Wk/Wv bf16 during qkv, then ATT (B,S,D) bf16
// R10: staging via VGPR (global_load_dwordx4 + ds_write_b128), NOT
// global_load_lds — r8/r9 counters showed gl_lds generated ~4x write
// amplification at TCC (WRITE_SIZE ~= 4 x staged bytes, 1.5 GB/dispatch).
// ---------------------------------------------------------------------------

typedef __bf16 bf16x8 __attribute__((ext_vector_type(8)));
typedef float floatx4 __attribute__((ext_vector_type(4)));
typedef float floatx16 __attribute__((ext_vector_type(16)));

#define MFMA16(A, B, C) __builtin_amdgcn_mfma_f32_16x16x32_bf16((A), (B), (C), 0, 0, 0)
#define MFMA32(A, B, C) __builtin_amdgcn_mfma_f32_32x32x16_bf16((A), (B), (C), 0, 0, 0)

#define S_LEN 2048
#define D_MODEL 1024
#define NHEAD 16
#define DHEAD 64
#define NTOK 4096
#define NEG_SENTINEL (-1.0e30f)

__device__ __forceinline__ short f2bf(float f) {
  union { float f; unsigned u; } v; v.f = f;
  unsigned r = v.u + 0x7fffu + ((v.u >> 16) & 1u);
  return (short)(r >> 16);
}
__device__ __forceinline__ bf16x8 ld_frag(const short* p) {
  return *(const bf16x8*)p;
}

// ---------------------------------------------------------------------------
__global__ __launch_bounds__(256) void cvt4_kernel(
    const float* __restrict__ x, const float* __restrict__ wq,
    const float* __restrict__ wk, const float* __restrict__ wv,
    short* __restrict__ xb, short* __restrict__ wqb,
    short* __restrict__ wkb, short* __restrict__ wvb) {
  const int y = blockIdx.y;
  const float* src = (y == 0) ? x : (y == 1) ? wq : (y == 2) ? wk : wv;
  short* dst = (y == 0) ? xb : (y == 1) ? wqb : (y == 2) ? wkb : wvb;
  const int n4 = ((y == 0) ? NTOK * D_MODEL : D_MODEL * D_MODEL) >> 2;
  for (int i = blockIdx.x * 256 + threadIdx.x; i < n4; i += gridDim.x * 256) {
    float4 v = ((const float4*)src)[i];
    short4 o;
    o.x = f2bf(v.x); o.y = f2bf(v.y); o.z = f2bf(v.z); o.w = f2bf(v.w);
    ((short4*)dst)[i] = o;
  }
}
__global__ __launch_bounds__(256) void cvt1_kernel(
    const float* __restrict__ src, short* __restrict__ dst, int n4) {
  for (int i = blockIdx.x * 256 + threadIdx.x; i < n4; i += gridDim.x * 256) {
    float4 v = ((const float4*)src)[i];
    short4 o;
    o.x = f2bf(v.x); o.y = f2bf(v.y); o.z = f2bf(v.z); o.w = f2bf(v.w);
    ((short4*)dst)[i] = o;
  }
}

// ---------------------------------------------------------------------------
// QKV + RoPE, 128x128 tile, VGPR->LDS staging, 4 waves.
// grid (256, 3): 32 M-tiles x 8 N-tiles; y: 0=Q,1=K,2=V.
// Epilogue: per-wave LDS transpose -> 16B coalesced stores (r9-proven).
// ---------------------------------------------------------------------------
__global__ __launch_bounds__(256) void qkv_rope_kernel(
    const short* __restrict__ xb,
    const short* __restrict__ Wqb, const short* __restrict__ Wkb,
    const short* __restrict__ Wvb,
    short* __restrict__ qws, short* __restrict__ kws, short* __restrict__ vtws) {
  __shared__ short SM[4 * 64 * 72];  // 36 KB; staging aliased in front
  short* As = SM;                    // 128*32 shorts
  short* Bs = SM + 4096;
  const int tid = threadIdx.x;
  const int lane = tid & 63, wave = tid >> 6;
  const int col = lane & 15, quad = lane >> 4;
  const int gemm = blockIdx.y;
  const int m0 = (blockIdx.x >> 3) * 128;
  const int n0 = (blockIdx.x & 7) * 128;
  const int wm = (wave >> 1) * 64, wn = (wave & 1) * 64;
  const short* W = (gemm == 0) ? Wqb : (gemm == 1) ? Wkb : Wvb;

  floatx4 acc[4][4];
#pragma unroll
  for (int i = 0; i < 4; ++i)
#pragma unroll
    for (int j = 0; j < 4; ++j) acc[i][j] = (floatx4){0.f, 0.f, 0.f, 0.f};

  const short* asrc = xb + (size_t)(m0 + (tid >> 2)) * D_MODEL + (tid & 3) * 8;
  const short* bsrc = W + (size_t)(n0 + (tid >> 2)) * D_MODEL + (tid & 3) * 8;

  for (int k0 = 0; k0 < D_MODEL; k0 += 32) {
    // global -> VGPR (issues before the barrier; overlaps prev MFMAs)
    bf16x8 a0 = ld_frag(asrc + k0);
    bf16x8 a1 = ld_frag(asrc + (size_t)64 * D_MODEL + k0);
    bf16x8 b0 = ld_frag(bsrc + k0);
    bf16x8 b1 = ld_frag(bsrc + (size_t)64 * D_MODEL + k0);
    __syncthreads();  // prev iteration's LDS reads done
    *(bf16x8*)&As[tid * 8] = a0;
    *(bf16x8*)&As[2048 + tid * 8] = a1;
    *(bf16x8*)&Bs[tid * 8] = b0;
    *(bf16x8*)&Bs[2048 + tid * 8] = b1;
    __syncthreads();  // staged data visible
    bf16x8 a[4], b[4];
#pragma unroll
    for (int mt = 0; mt < 4; ++mt)
      a[mt] = ld_frag(&As[(wm + mt * 16 + col) * 32 + quad * 8]);
#pragma unroll
    for (int nt = 0; nt < 4; ++nt)
      b[nt] = ld_frag(&Bs[(wn + nt * 16 + col) * 32 + quad * 8]);
#pragma unroll
    for (int mt = 0; mt < 4; ++mt)
#pragma unroll
      for (int nt = 0; nt < 4; ++nt)
        acc[mt][nt] = MFMA16(a[mt], b[nt], acc[mt][nt]);
  }

  // ---- epilogue: LDS transpose -> coalesced 16B stores -------------------
  __syncthreads();               // all waves done reading As/Bs
  short* Ep = &SM[wave * 64 * 72];
  const int hglob = (n0 + wn) >> 6;   // wave's n-range = exactly one head
  const int mbase = m0 + wm;          // 64-aligned, no batch-crossing
  const int bb = mbase >> 11;
  const int s0 = mbase & (S_LEN - 1);

  if (gemm == 2) {
    // V^T: LDS[dh][s_local]
#pragma unroll
    for (int mt = 0; mt < 4; ++mt)
#pragma unroll
      for (int nt = 0; nt < 4; ++nt) {
        int nl = nt * 16 + col;
#pragma unroll
        for (int r = 0; r < 4; ++r)
          Ep[nl * 72 + mt * 16 + quad * 4 + r] = f2bf(acc[mt][nt][r]);
      }
    __syncthreads();
    int4* d4 = (int4*)(vtws + ((size_t)(bb * NHEAD + hglob) * DHEAD + lane) * S_LEN + s0);
    const int4* src = (const int4*)&Ep[lane * 72];
#pragma unroll
    for (int i = 0; i < 8; ++i) d4[i] = src[i];
  } else {
    short* outp = (gemm == 0) ? qws : kws;
    const float qscale = (gemm == 0) ? 0.125f : 1.0f;  // 1/sqrt(Dh) into Q
#pragma unroll
    for (int nt = 0; nt < 4; ++nt) {
      int nl = nt * 16 + col;      // dh = nl (n-range head-aligned)
      int p = nl >> 1;
      float inv_freq = __expf(-0.28782313662425575f * (float)p);  // 1e4^(-p/32)
#pragma unroll
      for (int mt = 0; mt < 4; ++mt)
#pragma unroll
        for (int r = 0; r < 4; ++r) {
          int ml = mt * 16 + quad * 4 + r;
          int s = s0 + ml;
          float ang = (float)s * inv_freq;   // pos[s] == s (arange)
          float sn, c;
          sincosf(ang, &sn, &c);
          float val = acc[mt][nt][r];
          float partner = __shfl_xor(val, 1);  // n ^ 1 lives in lane ^ 1
          float o = ((nl & 1) == 0) ? (val * c - partner * sn)
                                    : (partner * sn + val * c);
          Ep[ml * 72 + nl] = f2bf(o * qscale);
        }
    }
    __syncthreads();
    int4* d4 = (int4*)(outp + ((size_t)(bb * NHEAD + hglob) * S_LEN + s0 + lane) * DHEAD);
    const int4* src = (const int4*)&Ep[lane * 72];
#pragma unroll
    for (int i = 0; i < 8; ++i) d4[i] = src[i];
  }
}

// ---------------------------------------------------------------------------
// Flash attention, 32x32x16 MFMA, transposed scores + transposed O.
// 1 wave/block, 32 q-rows, 64 keys/iter. grid 2048 x 64. (unchanged)
// ---------------------------------------------------------------------------
__global__ __launch_bounds__(64) void attn_kernel(
    const short* __restrict__ qws, const short* __restrict__ kws,
    const short* __restrict__ vtws, short* __restrict__ att) {
  const int lane = threadIdx.x;
  const int half = lane >> 5, l31 = lane & 31;
  const int qt = 63 - (blockIdx.x & 63);
  const int h = (blockIdx.x >> 6) & (NHEAD - 1);
  const int b = blockIdx.x >> 10;
  const int q0 = qt * 32;

  __shared__ short P[32][72];

  const short* qbase = qws + (size_t)(b * NHEAD + h) * S_LEN * DHEAD;
  const short* kbase = kws + (size_t)(b * NHEAD + h) * S_LEN * DHEAD;
  const short* vbase = vtws + (size_t)(b * NHEAD + h) * DHEAD * S_LEN;

  bf16x8 qf[4];
#pragma unroll
  for (int kc = 0; kc < 4; ++kc)
    qf[kc] = ld_frag(qbase + (size_t)(q0 + l31) * DHEAD + kc * 16 + half * 8);

  float m_i = NEG_SENTINEL, l_i = 0.f;
  floatx16 ot[2] = {};

  const int nit = (q0 + 32 + 63) >> 6;
  for (int it = 0; it < nit; ++it) {
    const int kt = it * 64;
    floatx16 sc[2];
#pragma unroll
    for (int s = 0; s < 2; ++s) {
      if (kt + s * 32 <= q0 + 31) {
        floatx16 a = {};
#pragma unroll
        for (int kc = 0; kc < 4; ++kc) {
          bf16x8 ka = ld_frag(kbase + (size_t)(kt + s * 32 + l31) * DHEAD + kc * 16 + half * 8);
          a = MFMA32(ka, qf[kc], a);
        }
        sc[s] = a;
      } else {
#pragma unroll
        for (int rg = 0; rg < 16; ++rg) sc[s][rg] = NEG_SENTINEL;
      }
    }
    if (kt + 63 > q0) {
#pragma unroll
      for (int s = 0; s < 2; ++s)
#pragma unroll
        for (int rg = 0; rg < 16; ++rg) {
          int key = kt + s * 32 + (rg & 3) + 8 * (rg >> 2) + 4 * half;
          if (key > q0 + l31) sc[s][rg] = NEG_SENTINEL;
        }
    }
    float rm = sc[0][0];
#pragma unroll
    for (int rg = 1; rg < 16; ++rg) rm = fmaxf(rm, sc[0][rg]);
#pragma unroll
    for (int rg = 0; rg < 16; ++rg) rm = fmaxf(rm, sc[1][rg]);
    rm = fmaxf(rm, __shfl_xor(rm, 32));
    float mnew = fmaxf(m_i, rm);
    float alpha = __expf(m_i - mnew);
    m_i = mnew;

    float rs = 0.f;
#pragma unroll
    for (int s = 0; s < 2; ++s)
#pragma unroll
      for (int g = 0; g < 4; ++g) {
        float p0 = __expf(sc[s][4 * g + 0] - mnew);
        float p1 = __expf(sc[s][4 * g + 1] - mnew);
        float p2 = __expf(sc[s][4 * g + 2] - mnew);
        float p3 = __expf(sc[s][4 * g + 3] - mnew);
        rs += (p0 + p1) + (p2 + p3);
        int kb = s * 32 + 8 * g + 4 * half;
        *(unsigned*)&P[l31][kb] =
            (unsigned)(unsigned short)f2bf(p0) | ((unsigned)(unsigned short)f2bf(p1) << 16);
        *(unsigned*)&P[l31][kb + 2] =
            (unsigned)(unsigned short)f2bf(p2) | ((unsigned)(unsigned short)f2bf(p3) << 16);
      }
    rs += __shfl_xor(rs, 32);
    l_i = l_i * alpha + rs;
#pragma unroll
    for (int dt = 0; dt < 2; ++dt)
#pragma unroll
      for (int rg = 0; rg < 16; ++rg) ot[dt][rg] *= alpha;

    __syncthreads();
#pragma unroll
    for (int kc = 0; kc < 4; ++kc) {
      bf16x8 pb = ld_frag(&P[l31][kc * 16 + half * 8]);
#pragma unroll
      for (int dt = 0; dt < 2; ++dt) {
        bf16x8 va = ld_frag(vbase + (size_t)(dt * 32 + l31) * S_LEN + kt + kc * 16 + half * 8);
        ot[dt] = MFMA32(va, pb, ot[dt]);
      }
    }
    __syncthreads();
  }

  float inv = 1.0f / l_i;
#pragma unroll
  for (int dt = 0; dt < 2; ++dt)
#pragma unroll
    for (int g = 0; g < 4; ++g) {
      int db = dt * 32 + 8 * g + 4 * half;
      float v0 = ot[dt][4 * g + 0] * inv, v1 = ot[dt][4 * g + 1] * inv;
      float v2 = ot[dt][4 * g + 2] * inv, v3 = ot[dt][4 * g + 3] * inv;
      *(unsigned*)&P[l31][db] =
          (unsigned)(unsigned short)f2bf(v0) | ((unsigned)(unsigned short)f2bf(v1) << 16);
      *(unsigned*)&P[l31][db + 2] =
          (unsigned)(unsigned short)f2bf(v2) | ((unsigned)(unsigned short)f2bf(v3) << 16);
    }
  __syncthreads();
  const int4* srcp = (const int4*)&P[l31][half * 32];
  int4* dstp = (int4*)(att + (size_t)(b * S_LEN + q0 + l31) * D_MODEL + h * DHEAD + half * 32);
#pragma unroll
  for (int i = 0; i < 4; ++i) dstp[i] = srcp[i];
}

// ---------------------------------------------------------------------------
// Output projection: out = att (bf16) @ Wo^T (bf16) -> fp32. VGPR staging.
// ---------------------------------------------------------------------------
__global__ __launch_bounds__(256) void out_gemm_kernel(
    const short* __restrict__ att, const short* __restrict__ Wob,
    float* __restrict__ out) {
  __shared__ short As[128 * 32];
  __shared__ short Bs[128 * 32];
  const int tid = threadIdx.x;
  const int lane = tid & 63, wave = tid >> 6;
  const int col = lane & 15, quad = lane >> 4;
  const int m0 = (blockIdx.x >> 3) * 128;
  const int n0 = (blockIdx.x & 7) * 128;
  const int wm = (wave >> 1) * 64, wn = (wave & 1) * 64;

  floatx4 acc[4][4];
#pragma unroll
  for (int i = 0; i < 4; ++i)
#pragma unroll
    for (int j = 0; j < 4; ++j) acc[i][j] = (floatx4){0.f, 0.f, 0.f, 0.f};

  const short* asrc = att + (size_t)(m0 + (tid >> 2)) * D_MODEL + (tid & 3) * 8;
  const short* bsrc = Wob + (size_t)(n0 + (tid >> 2)) * D_MODEL + (tid & 3) * 8;

  for (int k0 = 0; k0 < D_MODEL; k0 += 32) {
    bf16x8 a0 = ld_frag(asrc + k0);
    bf16x8 a1 = ld_frag(asrc + (size_t)64 * D_MODEL + k0);
    bf16x8 b0 = ld_frag(bsrc + k0);
    bf16x8 b1 = ld_frag(bsrc + (size_t)64 * D_MODEL + k0);
    __syncthreads();
    *(bf16x8*)&As[tid * 8] = a0;
    *(bf16x8*)&As[2048 + tid * 8] = a1;
    *(bf16x8*)&Bs[tid * 8] = b0;
    *(bf16x8*)&Bs[2048 + tid * 8] = b1;
    __syncthreads();
    bf16x8 a[4], b[4];
#pragma unroll
    for (int mt = 0; mt < 4; ++mt)
      a[mt] = ld_frag(&As[(wm + mt * 16 + col) * 32 + quad * 8]);
#pragma unroll
    for (int nt = 0; nt < 4; ++nt)
      b[nt] = ld_frag(&Bs[(wn + nt * 16 + col) * 32 + quad * 8]);
#pragma unroll
    for (int mt = 0; mt < 4; ++mt)
#pragma unroll
      for (int nt = 0; nt < 4; ++nt)
        acc[mt][nt] = MFMA16(a[mt], b[nt], acc[mt][nt]);
  }

#pragma unroll
  for (int mt = 0; mt < 4; ++mt)
#pragma unroll
    for (int nt = 0; nt < 4; ++nt) {
      int n = n0 + wn + nt * 16 + col;
#pragma unroll
      for (int r = 0; r < 4; ++r) {
        int m = m0 + wm + mt * 16 + quad * 4 + r;
        out[(size_t)m * D_MODEL + n] = acc[mt][nt][r];
      }
    }
}

// ---------------------------------------------------------------------------
extern "C" void kernel_launch(void* const* d_in, const int* in_sizes, int n_in,
                              void* d_out, int out_size, void* d_ws, size_t ws_size,
                              hipStream_t stream) {
  const float* x  = (const float*)d_in[0];
  const float* Wq = (const float*)d_in[2];
  const float* Wk = (const float*)d_in[3];
  const float* Wv = (const float*)d_in[4];
  const float* Wo = (const float*)d_in[5];
  float* out = (float*)d_out;

  const size_t TENS = (size_t)NTOK * D_MODEL;
  const size_t WELEM = (size_t)D_MODEL * D_MODEL;

  short* qws  = (short*)d_out;
  short* xb   = (short*)d_out + TENS;
  short* kws  = (short*)d_ws;
  short* vtws = kws + TENS;
  short* attws = vtws + TENS;
  short* wqb = attws;
  short* wkb = wqb + WELEM;
  short* wvb = wkb + WELEM;
  short* wob = kws;

  cvt4_kernel<<<dim3(256, 4), 256, 0, stream>>>(x, Wq, Wk, Wv, xb, wqb, wkb, wvb);
  qkv_rope_kernel<<<dim3(256, 3), 256, 0, stream>>>(xb, wqb, wkb, wvb, qws, kws, vtws);
  attn_kernel<<<dim3(2048), 64, 0, stream>>>(qws, kws, vtws, attws);
  cvt1_kernel<<<dim3(256), 256, 0, stream>>>(Wo, wob, (int)(WELEM >> 2));
  out_gemm_kernel<<<dim3(256), 256, 0, stream>>>(attws, wob, out);
}

// Round 11
// 366.657 us; speedup vs baseline: 1.7247x; 1.7247x over previous
//
#include <hip/hip_runtime.h>
#include <hip/hip_bf16.h>

// ---------------------------------------------------------------------------
// Causal MHA. B=2, S=2048, D=1024, H=16, Dh=64. Inputs fp32, output fp32.
// Internal bf16 MFMA.
// Memory plan (ws 24 MB, d_out 16 MB):
//   d_out[0:8MB]   Q   (B,H,S,Dh) bf16     d_out[8:16MB]  xb (4096,1024) bf16
//   ws[0:8MB]      K   (B,H,S,Dh) bf16 (dead after attn -> Wo-bf16)
//   ws[8:16MB]     VT  (B,H,Dh,S) bf16
//   ws[16:24MB]    Wq/Wk/Wv bf16 (6MB) + rope table (512KB) during qkv,
//                  then ATT (B,S,D) bf16 overwrites
// R11: (1) GEMM K-loops back to r7-style direct global->VGPR loads — the
// barriered LDS K-loop of r8-r10 carried an unexplained 1.5 GB/dispatch TCC
// write stream (falsified: not stores [r9], not gl_lds [r10]); (2) sincosf
// libcall removed from hot kernels (precomputed table) — the other candidate
// for scratch-generated write traffic.
// ---------------------------------------------------------------------------

typedef __bf16 bf16x8 __attribute__((ext_vector_type(8)));
typedef float floatx4 __attribute__((ext_vector_type(4)));
typedef float floatx16 __attribute__((ext_vector_type(16)));

#define MFMA16(A, B, C) __builtin_amdgcn_mfma_f32_16x16x32_bf16((A), (B), (C), 0, 0, 0)
#define MFMA32(A, B, C) __builtin_amdgcn_mfma_f32_32x32x16_bf16((A), (B), (C), 0, 0, 0)

#define S_LEN 2048
#define D_MODEL 1024
#define NHEAD 16
#define DHEAD 64
#define NTOK 4096
#define NEG_SENTINEL (-1.0e30f)

__device__ __forceinline__ short f2bf(float f) {
  union { float f; unsigned u; } v; v.f = f;
  unsigned r = v.u + 0x7fffu + ((v.u >> 16) & 1u);
  return (short)(r >> 16);
}
__device__ __forceinline__ bf16x8 ld_frag(const short* p) {
  return *(const bf16x8*)p;
}

// ---------------------------------------------------------------------------
// One-time RoPE table: tab[s*32+p] = (cos, sin)(s * 10000^(-p/32)).
// ---------------------------------------------------------------------------
__global__ __launch_bounds__(256) void rope_tab_kernel(float2* __restrict__ tab) {
  int i = blockIdx.x * 256 + threadIdx.x;  // 65536 = 2048*32
  int s = i >> 5, p = i & 31;
  float inv_freq = __expf(-0.28782313662425575f * (float)p);
  float ang = (float)s * inv_freq;
  float sn, c;
  sincosf(ang, &sn, &c);  // accurate; one-time cost
  tab[i] = make_float2(c, sn);
}

// ---------------------------------------------------------------------------
__global__ __launch_bounds__(256) void cvt4_kernel(
    const float* __restrict__ x, const float* __restrict__ wq,
    const float* __restrict__ wk, const float* __restrict__ wv,
    short* __restrict__ xb, short* __restrict__ wqb,
    short* __restrict__ wkb, short* __restrict__ wvb) {
  const int y = blockIdx.y;
  const float* src = (y == 0) ? x : (y == 1) ? wq : (y == 2) ? wk : wv;
  short* dst = (y == 0) ? xb : (y == 1) ? wqb : (y == 2) ? wkb : wvb;
  const int n4 = ((y == 0) ? NTOK * D_MODEL : D_MODEL * D_MODEL) >> 2;
  for (int i = blockIdx.x * 256 + threadIdx.x; i < n4; i += gridDim.x * 256) {
    float4 v = ((const float4*)src)[i];
    short4 o;
    o.x = f2bf(v.x); o.y = f2bf(v.y); o.z = f2bf(v.z); o.w = f2bf(v.w);
    ((short4*)dst)[i] = o;
  }
}
__global__ __launch_bounds__(256) void cvt1_kernel(
    const float* __restrict__ src, short* __restrict__ dst, int n4) {
  for (int i = blockIdx.x * 256 + threadIdx.x; i < n4; i += gridDim.x * 256) {
    float4 v = ((const float4*)src)[i];
    short4 o;
    o.x = f2bf(v.x); o.y = f2bf(v.y); o.z = f2bf(v.z); o.w = f2bf(v.w);
    ((short4*)dst)[i] = o;
  }
}

// ---------------------------------------------------------------------------
// QKV + RoPE. r7-style: wave = one 64x64 tile, direct global->VGPR loads,
// NO barriers. grid (256, 3) x 256; y: 0=Q,1=K,2=V.
// Epilogue: per-wave-private LDS transpose -> 16B coalesced stores.
// ---------------------------------------------------------------------------
__global__ __launch_bounds__(256) void qkv_rope_kernel(
    const short* __restrict__ xb,
    const short* __restrict__ Wqb, const short* __restrict__ Wkb,
    const short* __restrict__ Wvb,
    const float2* __restrict__ ropetab,
    short* __restrict__ qws, short* __restrict__ kws, short* __restrict__ vtws) {
  __shared__ short SM[4 * 64 * 72];  // per-wave 64x72 epilogue regions
  const int lane = threadIdx.x & 63;
  const int wave = threadIdx.x >> 6;
  const int col = lane & 15, quad = lane >> 4;
  const int gemm = blockIdx.y;
  const int tile = blockIdx.x * 4 + wave;  // 0..1023
  const int tm = tile >> 4;                // 0..63
  const int tn = tile & 15;                // 0..15 -> head = tn
  const short* W = (gemm == 0) ? Wqb : (gemm == 1) ? Wkb : Wvb;

  floatx4 acc[4][4];
#pragma unroll
  for (int i = 0; i < 4; ++i)
#pragma unroll
    for (int j = 0; j < 4; ++j) acc[i][j] = (floatx4){0.f, 0.f, 0.f, 0.f};

  const short* ap[4];
  const short* bp[4];
#pragma unroll
  for (int mt = 0; mt < 4; ++mt)
    ap[mt] = xb + (size_t)(tm * 64 + mt * 16 + col) * D_MODEL + quad * 8;
#pragma unroll
  for (int nt = 0; nt < 4; ++nt)
    bp[nt] = W + (size_t)(tn * 64 + nt * 16 + col) * D_MODEL + quad * 8;

  for (int k0 = 0; k0 < D_MODEL; k0 += 32) {
    bf16x8 a[4], b[4];
#pragma unroll
    for (int mt = 0; mt < 4; ++mt) a[mt] = ld_frag(ap[mt] + k0);
#pragma unroll
    for (int nt = 0; nt < 4; ++nt) b[nt] = ld_frag(bp[nt] + k0);
#pragma unroll
    for (int mt = 0; mt < 4; ++mt)
#pragma unroll
      for (int nt = 0; nt < 4; ++nt)
        acc[mt][nt] = MFMA16(a[mt], b[nt], acc[mt][nt]);
  }

  // ---- epilogue: per-wave LDS transpose -> 16B coalesced stores ----------
  short* Ep = &SM[wave * 64 * 72];
  const int mbase = tm * 64;            // 64-aligned, no batch-crossing
  const int bb = mbase >> 11;
  const int s0 = mbase & (S_LEN - 1);

  if (gemm == 2) {
    // V^T: LDS[dh][s_local]
#pragma unroll
    for (int mt = 0; mt < 4; ++mt)
#pragma unroll
      for (int nt = 0; nt < 4; ++nt) {
        int nl = nt * 16 + col;
#pragma unroll
        for (int r = 0; r < 4; ++r)
          Ep[nl * 72 + mt * 16 + quad * 4 + r] = f2bf(acc[mt][nt][r]);
      }
    // intra-wave LDS: compiler-inserted lgkmcnt waits suffice (no barrier)
    int4* d4 = (int4*)(vtws + ((size_t)(bb * NHEAD + tn) * DHEAD + lane) * S_LEN + s0);
    const int4* src = (const int4*)&Ep[lane * 72];
#pragma unroll
    for (int i = 0; i < 8; ++i) d4[i] = src[i];
  } else {
    short* outp = (gemm == 0) ? qws : kws;
    const float qscale = (gemm == 0) ? 0.125f : 1.0f;  // 1/sqrt(Dh) into Q
#pragma unroll
    for (int nt = 0; nt < 4; ++nt) {
      int nl = nt * 16 + col;      // dh = nl (head-aligned n-range)
      const float2* tp = ropetab + (nl >> 1);
#pragma unroll
      for (int mt = 0; mt < 4; ++mt)
#pragma unroll
        for (int r = 0; r < 4; ++r) {
          int ml = mt * 16 + quad * 4 + r;
          float2 cs = tp[(size_t)(s0 + ml) * 32];
          float val = acc[mt][nt][r];
          float partner = __shfl_xor(val, 1);  // dh^1 lives in lane^1
          float o = ((nl & 1) == 0) ? (val * cs.x - partner * cs.y)
                                    : (partner * cs.y + val * cs.x);
          Ep[ml * 72 + nl] = f2bf(o * qscale);
        }
    }
    int4* d4 = (int4*)(outp + ((size_t)(bb * NHEAD + tn) * S_LEN + s0 + lane) * DHEAD);
    const int4* src = (const int4*)&Ep[lane * 72];
#pragma unroll
    for (int i = 0; i < 8; ++i) d4[i] = src[i];
  }
}

// ---------------------------------------------------------------------------
// Flash attention, 32x32x16 MFMA, transposed scores + transposed O.
// 1 wave/block, 32 q-rows, 64 keys/iter. grid 2048 x 64. (unchanged)
// ---------------------------------------------------------------------------
__global__ __launch_bounds__(64) void attn_kernel(
    const short* __restrict__ qws, const short* __restrict__ kws,
    const short* __restrict__ vtws, short* __restrict__ att) {
  const int lane = threadIdx.x;
  const int half = lane >> 5, l31 = lane & 31;
  const int qt = 63 - (blockIdx.x & 63);
  const int h = (blockIdx.x >> 6) & (NHEAD - 1);
  const int b = blockIdx.x >> 10;
  const int q0 = qt * 32;

  __shared__ short P[32][72];

  const short* qbase = qws + (size_t)(b * NHEAD + h) * S_LEN * DHEAD;
  const short* kbase = kws + (size_t)(b * NHEAD + h) * S_LEN * DHEAD;
  const short* vbase = vtws + (size_t)(b * NHEAD + h) * DHEAD * S_LEN;

  bf16x8 qf[4];
#pragma unroll
  for (int kc = 0; kc < 4; ++kc)
    qf[kc] = ld_frag(qbase + (size_t)(q0 + l31) * DHEAD + kc * 16 + half * 8);

  float m_i = NEG_SENTINEL, l_i = 0.f;
  floatx16 ot[2] = {};

  const int nit = (q0 + 32 + 63) >> 6;
  for (int it = 0; it < nit; ++it) {
    const int kt = it * 64;
    floatx16 sc[2];
#pragma unroll
    for (int s = 0; s < 2; ++s) {
      if (kt + s * 32 <= q0 + 31) {
        floatx16 a = {};
#pragma unroll
        for (int kc = 0; kc < 4; ++kc) {
          bf16x8 ka = ld_frag(kbase + (size_t)(kt + s * 32 + l31) * DHEAD + kc * 16 + half * 8);
          a = MFMA32(ka, qf[kc], a);
        }
        sc[s] = a;
      } else {
#pragma unroll
        for (int rg = 0; rg < 16; ++rg) sc[s][rg] = NEG_SENTINEL;
      }
    }
    if (kt + 63 > q0) {
#pragma unroll
      for (int s = 0; s < 2; ++s)
#pragma unroll
        for (int rg = 0; rg < 16; ++rg) {
          int key = kt + s * 32 + (rg & 3) + 8 * (rg >> 2) + 4 * half;
          if (key > q0 + l31) sc[s][rg] = NEG_SENTINEL;
        }
    }
    float rm = sc[0][0];
#pragma unroll
    for (int rg = 1; rg < 16; ++rg) rm = fmaxf(rm, sc[0][rg]);
#pragma unroll
    for (int rg = 0; rg < 16; ++rg) rm = fmaxf(rm, sc[1][rg]);
    rm = fmaxf(rm, __shfl_xor(rm, 32));
    float mnew = fmaxf(m_i, rm);
    float alpha = __expf(m_i - mnew);
    m_i = mnew;

    float rs = 0.f;
#pragma unroll
    for (int s = 0; s < 2; ++s)
#pragma unroll
      for (int g = 0; g < 4; ++g) {
        float p0 = __expf(sc[s][4 * g + 0] - mnew);
        float p1 = __expf(sc[s][4 * g + 1] - mnew);
        float p2 = __expf(sc[s][4 * g + 2] - mnew);
        float p3 = __expf(sc[s][4 * g + 3] - mnew);
        rs += (p0 + p1) + (p2 + p3);
        int kb = s * 32 + 8 * g + 4 * half;
        *(unsigned*)&P[l31][kb] =
            (unsigned)(unsigned short)f2bf(p0) | ((unsigned)(unsigned short)f2bf(p1) << 16);
        *(unsigned*)&P[l31][kb + 2] =
            (unsigned)(unsigned short)f2bf(p2) | ((unsigned)(unsigned short)f2bf(p3) << 16);
      }
    rs += __shfl_xor(rs, 32);
    l_i = l_i * alpha + rs;
#pragma unroll
    for (int dt = 0; dt < 2; ++dt)
#pragma unroll
      for (int rg = 0; rg < 16; ++rg) ot[dt][rg] *= alpha;

    __syncthreads();
#pragma unroll
    for (int kc = 0; kc < 4; ++kc) {
      bf16x8 pb = ld_frag(&P[l31][kc * 16 + half * 8]);
#pragma unroll
      for (int dt = 0; dt < 2; ++dt) {
        bf16x8 va = ld_frag(vbase + (size_t)(dt * 32 + l31) * S_LEN + kt + kc * 16 + half * 8);
        ot[dt] = MFMA32(va, pb, ot[dt]);
      }
    }
    __syncthreads();
  }

  float inv = 1.0f / l_i;
#pragma unroll
  for (int dt = 0; dt < 2; ++dt)
#pragma unroll
    for (int g = 0; g < 4; ++g) {
      int db = dt * 32 + 8 * g + 4 * half;
      float v0 = ot[dt][4 * g + 0] * inv, v1 = ot[dt][4 * g + 1] * inv;
      float v2 = ot[dt][4 * g + 2] * inv, v3 = ot[dt][4 * g + 3] * inv;
      *(unsigned*)&P[l31][db] =
          (unsigned)(unsigned short)f2bf(v0) | ((unsigned)(unsigned short)f2bf(v1) << 16);
      *(unsigned*)&P[l31][db + 2] =
          (unsigned)(unsigned short)f2bf(v2) | ((unsigned)(unsigned short)f2bf(v3) << 16);
    }
  __syncthreads();
  const int4* srcp = (const int4*)&P[l31][half * 32];
  int4* dstp = (int4*)(att + (size_t)(b * S_LEN + q0 + l31) * D_MODEL + h * DHEAD + half * 32);
#pragma unroll
  for (int i = 0; i < 4; ++i) dstp[i] = srcp[i];
}

// ---------------------------------------------------------------------------
// Output projection: out = att (bf16) @ Wo^T (bf16) -> fp32. r7-style direct
// loads; scalar fp32 stores (16 consecutive lanes = 64B sectors).
// ---------------------------------------------------------------------------
__global__ __launch_bounds__(256) void out_gemm_kernel(
    const short* __restrict__ att, const short* __restrict__ Wob,
    float* __restrict__ out) {
  const int lane = threadIdx.x & 63;
  const int wave = threadIdx.x >> 6;
  const int col = lane & 15, quad = lane >> 4;
  const int tile = blockIdx.x * 4 + wave;
  const int tm = tile >> 4, tn = tile & 15;

  floatx4 acc[4][4];
#pragma unroll
  for (int i = 0; i < 4; ++i)
#pragma unroll
    for (int j = 0; j < 4; ++j) acc[i][j] = (floatx4){0.f, 0.f, 0.f, 0.f};

  const short* ap[4];
  const short* bp[4];
#pragma unroll
  for (int mt = 0; mt < 4; ++mt)
    ap[mt] = att + (size_t)(tm * 64 + mt * 16 + col) * D_MODEL + quad * 8;
#pragma unroll
  for (int nt = 0; nt < 4; ++nt)
    bp[nt] = Wob + (size_t)(tn * 64 + nt * 16 + col) * D_MODEL + quad * 8;

  for (int k0 = 0; k0 < D_MODEL; k0 += 32) {
    bf16x8 a[4], b[4];
#pragma unroll
    for (int mt = 0; mt < 4; ++mt) a[mt] = ld_frag(ap[mt] + k0);
#pragma unroll
    for (int nt = 0; nt < 4; ++nt) b[nt] = ld_frag(bp[nt] + k0);
#pragma unroll
    for (int mt = 0; mt < 4; ++mt)
#pragma unroll
      for (int nt = 0; nt < 4; ++nt)
        acc[mt][nt] = MFMA16(a[mt], b[nt], acc[mt][nt]);
  }

#pragma unroll
  for (int mt = 0; mt < 4; ++mt)
#pragma unroll
    for (int nt = 0; nt < 4; ++nt) {
      int n = tn * 64 + nt * 16 + col;
#pragma unroll
      for (int r = 0; r < 4; ++r) {
        int m = tm * 64 + mt * 16 + quad * 4 + r;
        out[(size_t)m * D_MODEL + n] = acc[mt][nt][r];
      }
    }
}

// ---------------------------------------------------------------------------
extern "C" void kernel_launch(void* const* d_in, const int* in_sizes, int n_in,
                              void* d_out, int out_size, void* d_ws, size_t ws_size,
                              hipStream_t stream) {
  const float* x  = (const float*)d_in[0];
  const float* Wq = (const float*)d_in[2];
  const float* Wk = (const float*)d_in[3];
  const float* Wv = (const float*)d_in[4];
  const float* Wo = (const float*)d_in[5];
  float* out = (float*)d_out;

  const size_t TENS = (size_t)NTOK * D_MODEL;
  const size_t WELEM = (size_t)D_MODEL * D_MODEL;

  short* qws  = (short*)d_out;
  short* xb   = (short*)d_out + TENS;
  short* kws  = (short*)d_ws;
  short* vtws = kws + TENS;
  short* attws = vtws + TENS;
  short* wqb = attws;                 // W-bf16 overlay (dead once attn writes)
  short* wkb = wqb + WELEM;
  short* wvb = wkb + WELEM;
  float2* ropetab = (float2*)(wvb + WELEM);  // 512 KB, dead once attn writes
  short* wob = kws;                   // K region, dead after attn

  rope_tab_kernel<<<dim3(256), 256, 0, stream>>>(ropetab);
  cvt4_kernel<<<dim3(256, 4), 256, 0, stream>>>(x, Wq, Wk, Wv, xb, wqb, wkb, wvb);
  qkv_rope_kernel<<<dim3(256, 3), 256, 0, stream>>>(xb, wqb, wkb, wvb, ropetab, qws, kws, vtws);
  attn_kernel<<<dim3(2048), 64, 0, stream>>>(qws, kws, vtws, attws);
  cvt1_kernel<<<dim3(256), 256, 0, stream>>>(Wo, wob, (int)(WELEM >> 2));
  out_gemm_kernel<<<dim3(256), 256, 0, stream>>>(attws, wob, out);
}

// Round 12
// 348.391 us; speedup vs baseline: 1.8151x; 1.0524x over previous
//
#include <hip/hip_runtime.h>
#include <hip/hip_bf16.h>

// ---------------------------------------------------------------------------
// Causal MHA. B=2, S=2048, D=1024, H=16, Dh=64. Inputs fp32, output fp32.
// Internal bf16 MFMA.
// Memory plan (ws 24 MB, d_out 16 MB):
//   d_out[0:8MB]   Q   (B,H,S,Dh) bf16     d_out[8:16MB]  xb (4096,1024) bf16
//   ws[0:8MB]      K   (B,H,S,Dh) bf16 (dead after attn -> Wo-bf16)
//   ws[8:16MB]     VT  (B,H,Dh,S) bf16
//   ws[16:24MB]    Wq/Wk/Wv bf16 (6MB) + rope table (512KB) during qkv,
//                  then ATT (B,S,D) bf16 overwrites
// R12: split-K flash attention — 4 waves per (b,h,qtile), each wave owns a
// strided quarter of the key tiles (private m/l/O + private LDS P), block
// merge at the end. r11 counters: attn Occupancy 11.7% (8 waves/CU cap from
// single-wave blocks), 80% latency stall -> parallelism deficit.
// ---------------------------------------------------------------------------

typedef __bf16 bf16x8 __attribute__((ext_vector_type(8)));
typedef float floatx4 __attribute__((ext_vector_type(4)));
typedef float floatx16 __attribute__((ext_vector_type(16)));

#define MFMA16(A, B, C) __builtin_amdgcn_mfma_f32_16x16x32_bf16((A), (B), (C), 0, 0, 0)
#define MFMA32(A, B, C) __builtin_amdgcn_mfma_f32_32x32x16_bf16((A), (B), (C), 0, 0, 0)

#define S_LEN 2048
#define D_MODEL 1024
#define NHEAD 16
#define DHEAD 64
#define NTOK 4096
#define NEG_SENTINEL (-1.0e30f)

__device__ __forceinline__ short f2bf(float f) {
  union { float f; unsigned u; } v; v.f = f;
  unsigned r = v.u + 0x7fffu + ((v.u >> 16) & 1u);
  return (short)(r >> 16);
}
__device__ __forceinline__ bf16x8 ld_frag(const short* p) {
  return *(const bf16x8*)p;
}

// ---------------------------------------------------------------------------
// One-time RoPE table: tab[s*32+p] = (cos, sin)(s * 10000^(-p/32)).
// ---------------------------------------------------------------------------
__global__ __launch_bounds__(256) void rope_tab_kernel(float2* __restrict__ tab) {
  int i = blockIdx.x * 256 + threadIdx.x;  // 65536 = 2048*32
  int s = i >> 5, p = i & 31;
  float inv_freq = __expf(-0.28782313662425575f * (float)p);
  float ang = (float)s * inv_freq;
  float sn, c;
  sincosf(ang, &sn, &c);  // accurate; one-time cost
  tab[i] = make_float2(c, sn);
}

// ---------------------------------------------------------------------------
__global__ __launch_bounds__(256) void cvt4_kernel(
    const float* __restrict__ x, const float* __restrict__ wq,
    const float* __restrict__ wk, const float* __restrict__ wv,
    short* __restrict__ xb, short* __restrict__ wqb,
    short* __restrict__ wkb, short* __restrict__ wvb) {
  const int y = blockIdx.y;
  const float* src = (y == 0) ? x : (y == 1) ? wq : (y == 2) ? wk : wv;
  short* dst = (y == 0) ? xb : (y == 1) ? wqb : (y == 2) ? wkb : wvb;
  const int n4 = ((y == 0) ? NTOK * D_MODEL : D_MODEL * D_MODEL) >> 2;
  for (int i = blockIdx.x * 256 + threadIdx.x; i < n4; i += gridDim.x * 256) {
    float4 v = ((const float4*)src)[i];
    short4 o;
    o.x = f2bf(v.x); o.y = f2bf(v.y); o.z = f2bf(v.z); o.w = f2bf(v.w);
    ((short4*)dst)[i] = o;
  }
}
__global__ __launch_bounds__(256) void cvt1_kernel(
    const float* __restrict__ src, short* __restrict__ dst, int n4) {
  for (int i = blockIdx.x * 256 + threadIdx.x; i < n4; i += gridDim.x * 256) {
    float4 v = ((const float4*)src)[i];
    short4 o;
    o.x = f2bf(v.x); o.y = f2bf(v.y); o.z = f2bf(v.z); o.w = f2bf(v.w);
    ((short4*)dst)[i] = o;
  }
}

// ---------------------------------------------------------------------------
// QKV + RoPE. Wave = one 64x64 tile, direct global->VGPR loads, NO barriers.
// grid (256, 3) x 256; y: 0=Q,1=K,2=V. (unchanged from r11)
// ---------------------------------------------------------------------------
__global__ __launch_bounds__(256) void qkv_rope_kernel(
    const short* __restrict__ xb,
    const short* __restrict__ Wqb, const short* __restrict__ Wkb,
    const short* __restrict__ Wvb,
    const float2* __restrict__ ropetab,
    short* __restrict__ qws, short* __restrict__ kws, short* __restrict__ vtws) {
  __shared__ short SM[4 * 64 * 72];
  const int lane = threadIdx.x & 63;
  const int wave = threadIdx.x >> 6;
  const int col = lane & 15, quad = lane >> 4;
  const int gemm = blockIdx.y;
  const int tile = blockIdx.x * 4 + wave;
  const int tm = tile >> 4;
  const int tn = tile & 15;
  const short* W = (gemm == 0) ? Wqb : (gemm == 1) ? Wkb : Wvb;

  floatx4 acc[4][4];
#pragma unroll
  for (int i = 0; i < 4; ++i)
#pragma unroll
    for (int j = 0; j < 4; ++j) acc[i][j] = (floatx4){0.f, 0.f, 0.f, 0.f};

  const short* ap[4];
  const short* bp[4];
#pragma unroll
  for (int mt = 0; mt < 4; ++mt)
    ap[mt] = xb + (size_t)(tm * 64 + mt * 16 + col) * D_MODEL + quad * 8;
#pragma unroll
  for (int nt = 0; nt < 4; ++nt)
    bp[nt] = W + (size_t)(tn * 64 + nt * 16 + col) * D_MODEL + quad * 8;

  for (int k0 = 0; k0 < D_MODEL; k0 += 32) {
    bf16x8 a[4], b[4];
#pragma unroll
    for (int mt = 0; mt < 4; ++mt) a[mt] = ld_frag(ap[mt] + k0);
#pragma unroll
    for (int nt = 0; nt < 4; ++nt) b[nt] = ld_frag(bp[nt] + k0);
#pragma unroll
    for (int mt = 0; mt < 4; ++mt)
#pragma unroll
      for (int nt = 0; nt < 4; ++nt)
        acc[mt][nt] = MFMA16(a[mt], b[nt], acc[mt][nt]);
  }

  short* Ep = &SM[wave * 64 * 72];
  const int mbase = tm * 64;
  const int bb = mbase >> 11;
  const int s0 = mbase & (S_LEN - 1);

  if (gemm == 2) {
#pragma unroll
    for (int mt = 0; mt < 4; ++mt)
#pragma unroll
      for (int nt = 0; nt < 4; ++nt) {
        int nl = nt * 16 + col;
#pragma unroll
        for (int r = 0; r < 4; ++r)
          Ep[nl * 72 + mt * 16 + quad * 4 + r] = f2bf(acc[mt][nt][r]);
      }
    int4* d4 = (int4*)(vtws + ((size_t)(bb * NHEAD + tn) * DHEAD + lane) * S_LEN + s0);
    const int4* src = (const int4*)&Ep[lane * 72];
#pragma unroll
    for (int i = 0; i < 8; ++i) d4[i] = src[i];
  } else {
    short* outp = (gemm == 0) ? qws : kws;
    const float qscale = (gemm == 0) ? 0.125f : 1.0f;
#pragma unroll
    for (int nt = 0; nt < 4; ++nt) {
      int nl = nt * 16 + col;
      const float2* tp = ropetab + (nl >> 1);
#pragma unroll
      for (int mt = 0; mt < 4; ++mt)
#pragma unroll
        for (int r = 0; r < 4; ++r) {
          int ml = mt * 16 + quad * 4 + r;
          float2 cs = tp[(size_t)(s0 + ml) * 32];
          float val = acc[mt][nt][r];
          float partner = __shfl_xor(val, 1);
          float o = ((nl & 1) == 0) ? (val * cs.x - partner * cs.y)
                                    : (partner * cs.y + val * cs.x);
          Ep[ml * 72 + nl] = f2bf(o * qscale);
        }
    }
    int4* d4 = (int4*)(outp + ((size_t)(bb * NHEAD + tn) * S_LEN + s0 + lane) * DHEAD);
    const int4* src = (const int4*)&Ep[lane * 72];
#pragma unroll
    for (int i = 0; i < 8; ++i) d4[i] = src[i];
  }
}

// ---------------------------------------------------------------------------
// Split-K flash attention. Block = 256 threads = 4 waves per (b,h,32-q-tile);
// wave w handles key-tiles it = w, w+4, ... (private m/l/O, private LDS P;
// intra-wave LDS round-trip needs no barrier — r11-proven). Block merge:
// m/l via LDS + serialized O accumulation, then coalesced store. grid 2048.
// ---------------------------------------------------------------------------
__global__ __launch_bounds__(256) void attn_kernel(
    const short* __restrict__ qws, const short* __restrict__ kws,
    const short* __restrict__ vtws, short* __restrict__ att) {
  const int tid = threadIdx.x;
  const int wv = tid >> 6;
  const int lane = tid & 63;
  const int half = lane >> 5, l31 = lane & 31;
  const int qt = 63 - (blockIdx.x & 63);  // long blocks first
  const int h = (blockIdx.x >> 6) & (NHEAD - 1);
  const int b = blockIdx.x >> 10;
  const int q0 = qt * 32;

  __shared__ short P[4][32][72];   // per-wave P buffers
  __shared__ float ml[2][4][32];   // [0]=m, [1]=l  per wave per q
  __shared__ float Obuf[64][33];   // merged O^T (d, q) fp32

  const short* qbase = qws + (size_t)(b * NHEAD + h) * S_LEN * DHEAD;
  const short* kbase = kws + (size_t)(b * NHEAD + h) * S_LEN * DHEAD;
  const short* vbase = vtws + (size_t)(b * NHEAD + h) * DHEAD * S_LEN;

  bf16x8 qf[4];
#pragma unroll
  for (int kc = 0; kc < 4; ++kc)
    qf[kc] = ld_frag(qbase + (size_t)(q0 + l31) * DHEAD + kc * 16 + half * 8);

  float m_i = NEG_SENTINEL, l_i = 0.f;
  floatx16 ot[2] = {};  // O^T: d = dt*32+(rg&3)+8*(rg>>2)+4*half, q = l31

  const int nit = (q0 + 32 + 63) >> 6;  // total 64-key tiles
  for (int it = wv; it < nit; it += 4) {
    const int kt = it * 64;
    floatx16 sc[2];
#pragma unroll
    for (int s = 0; s < 2; ++s) {
      if (kt + s * 32 <= q0 + 31) {  // wave-uniform
        floatx16 a = {};
#pragma unroll
        for (int kc = 0; kc < 4; ++kc) {
          bf16x8 ka = ld_frag(kbase + (size_t)(kt + s * 32 + l31) * DHEAD + kc * 16 + half * 8);
          a = MFMA32(ka, qf[kc], a);
        }
        sc[s] = a;
      } else {
#pragma unroll
        for (int rg = 0; rg < 16; ++rg) sc[s][rg] = NEG_SENTINEL;
      }
    }
    if (kt + 63 > q0) {  // wave-uniform causal-mask tile
#pragma unroll
      for (int s = 0; s < 2; ++s)
#pragma unroll
        for (int rg = 0; rg < 16; ++rg) {
          int key = kt + s * 32 + (rg & 3) + 8 * (rg >> 2) + 4 * half;
          if (key > q0 + l31) sc[s][rg] = NEG_SENTINEL;
        }
    }
    float rm = sc[0][0];
#pragma unroll
    for (int rg = 1; rg < 16; ++rg) rm = fmaxf(rm, sc[0][rg]);
#pragma unroll
    for (int rg = 0; rg < 16; ++rg) rm = fmaxf(rm, sc[1][rg]);
    rm = fmaxf(rm, __shfl_xor(rm, 32));
    float mnew = fmaxf(m_i, rm);
    float alpha = __expf(m_i - mnew);
    m_i = mnew;

    float rs = 0.f;
#pragma unroll
    for (int s = 0; s < 2; ++s)
#pragma unroll
      for (int g = 0; g < 4; ++g) {
        float p0 = __expf(sc[s][4 * g + 0] - mnew);
        float p1 = __expf(sc[s][4 * g + 1] - mnew);
        float p2 = __expf(sc[s][4 * g + 2] - mnew);
        float p3 = __expf(sc[s][4 * g + 3] - mnew);
        rs += (p0 + p1) + (p2 + p3);
        int kb = s * 32 + 8 * g + 4 * half;
        *(unsigned*)&P[wv][l31][kb] =
            (unsigned)(unsigned short)f2bf(p0) | ((unsigned)(unsigned short)f2bf(p1) << 16);
        *(unsigned*)&P[wv][l31][kb + 2] =
            (unsigned)(unsigned short)f2bf(p2) | ((unsigned)(unsigned short)f2bf(p3) << 16);
      }
    rs += __shfl_xor(rs, 32);
    l_i = l_i * alpha + rs;
#pragma unroll
    for (int dt = 0; dt < 2; ++dt)
#pragma unroll
      for (int rg = 0; rg < 16; ++rg) ot[dt][rg] *= alpha;

    // PV (intra-wave LDS round-trip; in-order LDS + compiler lgkmcnt waits)
#pragma unroll
    for (int kc = 0; kc < 4; ++kc) {
      bf16x8 pb = ld_frag(&P[wv][l31][kc * 16 + half * 8]);
#pragma unroll
      for (int dt = 0; dt < 2; ++dt) {
        bf16x8 va = ld_frag(vbase + (size_t)(dt * 32 + l31) * S_LEN + kt + kc * 16 + half * 8);
        ot[dt] = MFMA32(va, pb, ot[dt]);
      }
    }
  }

  // ---- block merge ------------------------------------------------------
  ml[0][wv][l31] = m_i;   // replicated across halves (same value)
  ml[1][wv][l31] = l_i;
  __syncthreads();
  float m0 = ml[0][0][l31], m1 = ml[0][1][l31];
  float m2 = ml[0][2][l31], m3 = ml[0][3][l31];
  float mtot = fmaxf(fmaxf(m0, m1), fmaxf(m2, m3));
  float sw = __expf(m_i - mtot);  // idle wave: exp(-1e30-mtot) = 0

  if (wv == 0) {
#pragma unroll
    for (int dt = 0; dt < 2; ++dt)
#pragma unroll
      for (int rg = 0; rg < 16; ++rg) {
        int d = dt * 32 + (rg & 3) + 8 * (rg >> 2) + 4 * half;
        Obuf[d][l31] = ot[dt][rg] * sw;
      }
  }
  __syncthreads();
#pragma unroll
  for (int w = 1; w < 4; ++w) {
    if (wv == w) {
#pragma unroll
      for (int dt = 0; dt < 2; ++dt)
#pragma unroll
        for (int rg = 0; rg < 16; ++rg) {
          int d = dt * 32 + (rg & 3) + 8 * (rg >> 2) + 4 * half;
          Obuf[d][l31] += ot[dt][rg] * sw;
        }
    }
    __syncthreads();
  }

  // ---- final normalize + coalesced store (128B per q-row) ---------------
  const int q = tid >> 3;            // 0..31
  const int d0 = (tid & 7) * 8;      // 0,8,..,56
  float mm0 = ml[0][0][q], mm1 = ml[0][1][q], mm2 = ml[0][2][q], mm3 = ml[0][3][q];
  float mt2 = fmaxf(fmaxf(mm0, mm1), fmaxf(mm2, mm3));
  float lt = ml[1][0][q] * __expf(mm0 - mt2) + ml[1][1][q] * __expf(mm1 - mt2) +
             ml[1][2][q] * __expf(mm2 - mt2) + ml[1][3][q] * __expf(mm3 - mt2);
  float inv = 1.0f / lt;  // lt >= 1
  unsigned u[4];
#pragma unroll
  for (int i = 0; i < 4; ++i) {
    float v0 = Obuf[d0 + 2 * i][q] * inv;
    float v1 = Obuf[d0 + 2 * i + 1][q] * inv;
    u[i] = (unsigned)(unsigned short)f2bf(v0) | ((unsigned)(unsigned short)f2bf(v1) << 16);
  }
  int4* dst = (int4*)(att + (size_t)(b * S_LEN + q0 + q) * D_MODEL + h * DHEAD + d0);
  *dst = make_int4(u[0], u[1], u[2], u[3]);
}

// ---------------------------------------------------------------------------
// Output projection: out = att (bf16) @ Wo^T (bf16) -> fp32. (unchanged)
// ---------------------------------------------------------------------------
__global__ __launch_bounds__(256) void out_gemm_kernel(
    const short* __restrict__ att, const short* __restrict__ Wob,
    float* __restrict__ out) {
  const int lane = threadIdx.x & 63;
  const int wave = threadIdx.x >> 6;
  const int col = lane & 15, quad = lane >> 4;
  const int tile = blockIdx.x * 4 + wave;
  const int tm = tile >> 4, tn = tile & 15;

  floatx4 acc[4][4];
#pragma unroll
  for (int i = 0; i < 4; ++i)
#pragma unroll
    for (int j = 0; j < 4; ++j) acc[i][j] = (floatx4){0.f, 0.f, 0.f, 0.f};

  const short* ap[4];
  const short* bp[4];
#pragma unroll
  for (int mt = 0; mt < 4; ++mt)
    ap[mt] = att + (size_t)(tm * 64 + mt * 16 + col) * D_MODEL + quad * 8;
#pragma unroll
  for (int nt = 0; nt < 4; ++nt)
    bp[nt] = Wob + (size_t)(tn * 64 + nt * 16 + col) * D_MODEL + quad * 8;

  for (int k0 = 0; k0 < D_MODEL; k0 += 32) {
    bf16x8 a[4], b[4];
#pragma unroll
    for (int mt = 0; mt < 4; ++mt) a[mt] = ld_frag(ap[mt] + k0);
#pragma unroll
    for (int nt = 0; nt < 4; ++nt) b[nt] = ld_frag(bp[nt] + k0);
#pragma unroll
    for (int mt = 0; mt < 4; ++mt)
#pragma unroll
      for (int nt = 0; nt < 4; ++nt)
        acc[mt][nt] = MFMA16(a[mt], b[nt], acc[mt][nt]);
  }

#pragma unroll
  for (int mt = 0; mt < 4; ++mt)
#pragma unroll
    for (int nt = 0; nt < 4; ++nt) {
      int n = tn * 64 + nt * 16 + col;
#pragma unroll
      for (int r = 0; r < 4; ++r) {
        int m = tm * 64 + mt * 16 + quad * 4 + r;
        out[(size_t)m * D_MODEL + n] = acc[mt][nt][r];
      }
    }
}

// ---------------------------------------------------------------------------
extern "C" void kernel_launch(void* const* d_in, const int* in_sizes, int n_in,
                              void* d_out, int out_size, void* d_ws, size_t ws_size,
                              hipStream_t stream) {
  const float* x  = (const float*)d_in[0];
  const float* Wq = (const float*)d_in[2];
  const float* Wk = (const float*)d_in[3];
  const float* Wv = (const float*)d_in[4];
  const float* Wo = (const float*)d_in[5];
  float* out = (float*)d_out;

  const size_t TENS = (size_t)NTOK * D_MODEL;
  const size_t WELEM = (size_t)D_MODEL * D_MODEL;

  short* qws  = (short*)d_out;
  short* xb   = (short*)d_out + TENS;
  short* kws  = (short*)d_ws;
  short* vtws = kws + TENS;
  short* attws = vtws + TENS;
  short* wqb = attws;
  short* wkb = wqb + WELEM;
  short* wvb = wkb + WELEM;
  float2* ropetab = (float2*)(wvb + WELEM);
  short* wob = kws;

  rope_tab_kernel<<<dim3(256), 256, 0, stream>>>(ropetab);
  cvt4_kernel<<<dim3(256, 4), 256, 0, stream>>>(x, Wq, Wk, Wv, xb, wqb, wkb, wvb);
  qkv_rope_kernel<<<dim3(256, 3), 256, 0, stream>>>(xb, wqb, wkb, wvb, ropetab, qws, kws, vtws);
  attn_kernel<<<dim3(2048), 256, 0, stream>>>(qws, kws, vtws, attws);
  cvt1_kernel<<<dim3(256), 256, 0, stream>>>(Wo, wob, (int)(WELEM >> 2));
  out_gemm_kernel<<<dim3(256), 256, 0, stream>>>(attws, wob, out);
}

// Round 13
// 309.959 us; speedup vs baseline: 2.0401x; 1.1240x over previous
//
#include <hip/hip_runtime.h>
#include <hip/hip_bf16.h>

// ---------------------------------------------------------------------------
// Causal MHA. B=2, S=2048, D=1024, H=16, Dh=64. Inputs fp32, output fp32.
// Internal bf16 MFMA.
// Memory plan (ws 24 MB, d_out 16 MB):
//   d_out[0:8MB]   Q   (B,H,S,Dh) bf16     d_out[8:16MB]  xb (4096,1024) bf16
//   ws[0:8MB]      K   (B,H,S,Dh) bf16 (dead after attn -> Wo-bf16)
//   ws[8:16MB]     VT  (B,H,Dh,S) bf16
//   ws[16:24MB]    Wq/Wk/Wv bf16 (6MB) + rope table (512KB) during qkv,
//                  then ATT (B,S,D) bf16 overwrites
// R13: attn software pipelining — V loads hoisted before softmax, K double-
// buffered across iterations (r12 post-mortem: wall == Sigma-iters x ~2100cyc
// serialized chain; extra waves didn't overlap, so hide latency with ILP),
// plus XCD co-location swizzle (same (b,h) -> same XCD's L2).
// ---------------------------------------------------------------------------

typedef __bf16 bf16x8 __attribute__((ext_vector_type(8)));
typedef float floatx4 __attribute__((ext_vector_type(4)));
typedef float floatx16 __attribute__((ext_vector_type(16)));

#define MFMA16(A, B, C) __builtin_amdgcn_mfma_f32_16x16x32_bf16((A), (B), (C), 0, 0, 0)
#define MFMA32(A, B, C) __builtin_amdgcn_mfma_f32_32x32x16_bf16((A), (B), (C), 0, 0, 0)

#define S_LEN 2048
#define D_MODEL 1024
#define NHEAD 16
#define DHEAD 64
#define NTOK 4096
#define NEG_SENTINEL (-1.0e30f)

__device__ __forceinline__ short f2bf(float f) {
  union { float f; unsigned u; } v; v.f = f;
  unsigned r = v.u + 0x7fffu + ((v.u >> 16) & 1u);
  return (short)(r >> 16);
}
__device__ __forceinline__ bf16x8 ld_frag(const short* p) {
  return *(const bf16x8*)p;
}

// ---------------------------------------------------------------------------
// One-time RoPE table: tab[s*32+p] = (cos, sin)(s * 10000^(-p/32)).
// ---------------------------------------------------------------------------
__global__ __launch_bounds__(256) void rope_tab_kernel(float2* __restrict__ tab) {
  int i = blockIdx.x * 256 + threadIdx.x;  // 65536 = 2048*32
  int s = i >> 5, p = i & 31;
  float inv_freq = __expf(-0.28782313662425575f * (float)p);
  float ang = (float)s * inv_freq;
  float sn, c;
  sincosf(ang, &sn, &c);  // accurate; one-time cost
  tab[i] = make_float2(c, sn);
}

// ---------------------------------------------------------------------------
__global__ __launch_bounds__(256) void cvt4_kernel(
    const float* __restrict__ x, const float* __restrict__ wq,
    const float* __restrict__ wk, const float* __restrict__ wv,
    short* __restrict__ xb, short* __restrict__ wqb,
    short* __restrict__ wkb, short* __restrict__ wvb) {
  const int y = blockIdx.y;
  const float* src = (y == 0) ? x : (y == 1) ? wq : (y == 2) ? wk : wv;
  short* dst = (y == 0) ? xb : (y == 1) ? wqb : (y == 2) ? wkb : wvb;
  const int n4 = ((y == 0) ? NTOK * D_MODEL : D_MODEL * D_MODEL) >> 2;
  for (int i = blockIdx.x * 256 + threadIdx.x; i < n4; i += gridDim.x * 256) {
    float4 v = ((const float4*)src)[i];
    short4 o;
    o.x = f2bf(v.x); o.y = f2bf(v.y); o.z = f2bf(v.z); o.w = f2bf(v.w);
    ((short4*)dst)[i] = o;
  }
}
__global__ __launch_bounds__(256) void cvt1_kernel(
    const float* __restrict__ src, short* __restrict__ dst, int n4) {
  for (int i = blockIdx.x * 256 + threadIdx.x; i < n4; i += gridDim.x * 256) {
    float4 v = ((const float4*)src)[i];
    short4 o;
    o.x = f2bf(v.x); o.y = f2bf(v.y); o.z = f2bf(v.z); o.w = f2bf(v.w);
    ((short4*)dst)[i] = o;
  }
}

// ---------------------------------------------------------------------------
// QKV + RoPE. Wave = one 64x64 tile, direct global->VGPR loads, NO barriers.
// grid (256, 3) x 256; y: 0=Q,1=K,2=V. (unchanged from r11/r12)
// ---------------------------------------------------------------------------
__global__ __launch_bounds__(256) void qkv_rope_kernel(
    const short* __restrict__ xb,
    const short* __restrict__ Wqb, const short* __restrict__ Wkb,
    const short* __restrict__ Wvb,
    const float2* __restrict__ ropetab,
    short* __restrict__ qws, short* __restrict__ kws, short* __restrict__ vtws) {
  __shared__ short SM[4 * 64 * 72];
  const int lane = threadIdx.x & 63;
  const int wave = threadIdx.x >> 6;
  const int col = lane & 15, quad = lane >> 4;
  const int gemm = blockIdx.y;
  const int tile = blockIdx.x * 4 + wave;
  const int tm = tile >> 4;
  const int tn = tile & 15;
  const short* W = (gemm == 0) ? Wqb : (gemm == 1) ? Wkb : Wvb;

  floatx4 acc[4][4];
#pragma unroll
  for (int i = 0; i < 4; ++i)
#pragma unroll
    for (int j = 0; j < 4; ++j) acc[i][j] = (floatx4){0.f, 0.f, 0.f, 0.f};

  const short* ap[4];
  const short* bp[4];
#pragma unroll
  for (int mt = 0; mt < 4; ++mt)
    ap[mt] = xb + (size_t)(tm * 64 + mt * 16 + col) * D_MODEL + quad * 8;
#pragma unroll
  for (int nt = 0; nt < 4; ++nt)
    bp[nt] = W + (size_t)(tn * 64 + nt * 16 + col) * D_MODEL + quad * 8;

  for (int k0 = 0; k0 < D_MODEL; k0 += 32) {
    bf16x8 a[4], b[4];
#pragma unroll
    for (int mt = 0; mt < 4; ++mt) a[mt] = ld_frag(ap[mt] + k0);
#pragma unroll
    for (int nt = 0; nt < 4; ++nt) b[nt] = ld_frag(bp[nt] + k0);
#pragma unroll
    for (int mt = 0; mt < 4; ++mt)
#pragma unroll
      for (int nt = 0; nt < 4; ++nt)
        acc[mt][nt] = MFMA16(a[mt], b[nt], acc[mt][nt]);
  }

  short* Ep = &SM[wave * 64 * 72];
  const int mbase = tm * 64;
  const int bb = mbase >> 11;
  const int s0 = mbase & (S_LEN - 1);

  if (gemm == 2) {
#pragma unroll
    for (int mt = 0; mt < 4; ++mt)
#pragma unroll
      for (int nt = 0; nt < 4; ++nt) {
        int nl = nt * 16 + col;
#pragma unroll
        for (int r = 0; r < 4; ++r)
          Ep[nl * 72 + mt * 16 + quad * 4 + r] = f2bf(acc[mt][nt][r]);
      }
    int4* d4 = (int4*)(vtws + ((size_t)(bb * NHEAD + tn) * DHEAD + lane) * S_LEN + s0);
    const int4* src = (const int4*)&Ep[lane * 72];
#pragma unroll
    for (int i = 0; i < 8; ++i) d4[i] = src[i];
  } else {
    short* outp = (gemm == 0) ? qws : kws;
    const float qscale = (gemm == 0) ? 0.125f : 1.0f;
#pragma unroll
    for (int nt = 0; nt < 4; ++nt) {
      int nl = nt * 16 + col;
      const float2* tp = ropetab + (nl >> 1);
#pragma unroll
      for (int mt = 0; mt < 4; ++mt)
#pragma unroll
        for (int r = 0; r < 4; ++r) {
          int ml = mt * 16 + quad * 4 + r;
          float2 cs = tp[(size_t)(s0 + ml) * 32];
          float val = acc[mt][nt][r];
          float partner = __shfl_xor(val, 1);
          float o = ((nl & 1) == 0) ? (val * cs.x - partner * cs.y)
                                    : (partner * cs.y + val * cs.x);
          Ep[ml * 72 + nl] = f2bf(o * qscale);
        }
    }
    int4* d4 = (int4*)(outp + ((size_t)(bb * NHEAD + tn) * S_LEN + s0 + lane) * DHEAD);
    const int4* src = (const int4*)&Ep[lane * 72];
#pragma unroll
    for (int i = 0; i < 8; ++i) d4[i] = src[i];
  }
}

// ---------------------------------------------------------------------------
// Split-K flash attention, software-pipelined. Block = 4 waves per
// (b,h,32-q-tile); wave w handles key-tiles it = w, w+4, ...
// Pipeline: V loads at iter top (overlap softmax), K double-buffered
// (next-iter K issues right after score MFMAs). XCD swizzle: bh in low 5
// bits of blockIdx so one (b,h)'s K/V stay in one XCD's L2. grid 2048x256.
// ---------------------------------------------------------------------------
__global__ __launch_bounds__(256) void attn_kernel(
    const short* __restrict__ qws, const short* __restrict__ kws,
    const short* __restrict__ vtws, short* __restrict__ att) {
  const int tid = threadIdx.x;
  const int wv = tid >> 6;
  const int lane = tid & 63;
  const int half = lane >> 5, l31 = lane & 31;
  const int bh = blockIdx.x & 31;          // consecutive blocks -> different
  const int b = bh >> 4, h = bh & 15;      // (b,h): same (b,h) lands on the
  const int qt = 63 - (blockIdx.x >> 5);   // same XCD (round-robin heuristic)
  const int q0 = qt * 32;

  __shared__ short P[4][32][72];   // per-wave P buffers
  __shared__ float ml[2][4][32];   // [0]=m, [1]=l  per wave per q
  __shared__ float Obuf[64][33];   // merged O^T (d, q) fp32

  const short* qbase = qws + (size_t)(b * NHEAD + h) * S_LEN * DHEAD;
  const short* kbase = kws + (size_t)(b * NHEAD + h) * S_LEN * DHEAD;
  const short* vbase = vtws + (size_t)(b * NHEAD + h) * DHEAD * S_LEN;

  bf16x8 qf[4];
#pragma unroll
  for (int kc = 0; kc < 4; ++kc)
    qf[kc] = ld_frag(qbase + (size_t)(q0 + l31) * DHEAD + kc * 16 + half * 8);

  float m_i = NEG_SENTINEL, l_i = 0.f;
  floatx16 ot[2] = {};  // O^T: d = dt*32+(rg&3)+8*(rg>>2)+4*half, q = l31

  const int nit = (q0 + 32 + 63) >> 6;  // total 64-key tiles

  bf16x8 kfA[2][4], kfB[2][4];  // K double buffer
  auto loadK = [&](bf16x8 (&dst)[2][4], int tkt) {
#pragma unroll
    for (int s = 0; s < 2; ++s) {
      if (tkt + s * 32 <= q0 + 31) {  // wave-uniform validity
        const short* kr = kbase + (size_t)(tkt + s * 32 + l31) * DHEAD + half * 8;
#pragma unroll
        for (int kc = 0; kc < 4; ++kc) dst[s][kc] = ld_frag(kr + kc * 16);
      }
    }
  };

  int it = wv;
  if (it < nit) loadK(kfA, it * 64);  // prologue

  for (; it < nit; it += 4) {
    const int kt = it * 64;
    // --- V loads first: no deps, latency overlaps the whole softmax chain
    bf16x8 vf[4][2];
#pragma unroll
    for (int kc = 0; kc < 4; ++kc)
#pragma unroll
      for (int dt = 0; dt < 2; ++dt)
        vf[kc][dt] = ld_frag(vbase + (size_t)(dt * 32 + l31) * S_LEN + kt + kc * 16 + half * 8);
    // --- scores from the prefetched K registers
    floatx16 sc[2];
#pragma unroll
    for (int s = 0; s < 2; ++s) {
      if (kt + s * 32 <= q0 + 31) {
        floatx16 a = {};
#pragma unroll
        for (int kc = 0; kc < 4; ++kc) a = MFMA32(kfA[s][kc], qf[kc], a);
        sc[s] = a;
      } else {
#pragma unroll
        for (int rg = 0; rg < 16; ++rg) sc[s][rg] = NEG_SENTINEL;
      }
    }
    // --- prefetch next iteration's K (overlaps softmax + PV)
    const bool havenext = (it + 4 < nit);
    if (havenext) loadK(kfB, (it + 4) * 64);

    // --- causal mask (wave-uniform skip for full tiles)
    if (kt + 63 > q0) {
#pragma unroll
      for (int s = 0; s < 2; ++s)
#pragma unroll
        for (int rg = 0; rg < 16; ++rg) {
          int key = kt + s * 32 + (rg & 3) + 8 * (rg >> 2) + 4 * half;
          if (key > q0 + l31) sc[s][rg] = NEG_SENTINEL;
        }
    }
    // --- online softmax: in-lane reduce + 1 shuffle
    float rm = sc[0][0];
#pragma unroll
    for (int rg = 1; rg < 16; ++rg) rm = fmaxf(rm, sc[0][rg]);
#pragma unroll
    for (int rg = 0; rg < 16; ++rg) rm = fmaxf(rm, sc[1][rg]);
    rm = fmaxf(rm, __shfl_xor(rm, 32));
    float mnew = fmaxf(m_i, rm);
    float alpha = __expf(m_i - mnew);
    m_i = mnew;

    float rs = 0.f;
#pragma unroll
    for (int s = 0; s < 2; ++s)
#pragma unroll
      for (int g = 0; g < 4; ++g) {
        float p0 = __expf(sc[s][4 * g + 0] - mnew);
        float p1 = __expf(sc[s][4 * g + 1] - mnew);
        float p2 = __expf(sc[s][4 * g + 2] - mnew);
        float p3 = __expf(sc[s][4 * g + 3] - mnew);
        rs += (p0 + p1) + (p2 + p3);
        int kb = s * 32 + 8 * g + 4 * half;
        *(unsigned*)&P[wv][l31][kb] =
            (unsigned)(unsigned short)f2bf(p0) | ((unsigned)(unsigned short)f2bf(p1) << 16);
        *(unsigned*)&P[wv][l31][kb + 2] =
            (unsigned)(unsigned short)f2bf(p2) | ((unsigned)(unsigned short)f2bf(p3) << 16);
      }
    rs += __shfl_xor(rs, 32);
    l_i = l_i * alpha + rs;
#pragma unroll
    for (int dt = 0; dt < 2; ++dt)
#pragma unroll
      for (int rg = 0; rg < 16; ++rg) ot[dt][rg] *= alpha;

    // --- PV from prefetched V registers (intra-wave LDS round-trip for P)
#pragma unroll
    for (int kc = 0; kc < 4; ++kc) {
      bf16x8 pb = ld_frag(&P[wv][l31][kc * 16 + half * 8]);
#pragma unroll
      for (int dt = 0; dt < 2; ++dt)
        ot[dt] = MFMA32(vf[kc][dt], pb, ot[dt]);
    }
    // --- rotate K buffers
    if (havenext) {
#pragma unroll
      for (int s = 0; s < 2; ++s)
#pragma unroll
        for (int kc = 0; kc < 4; ++kc) kfA[s][kc] = kfB[s][kc];
    }
  }

  // ---- block merge ------------------------------------------------------
  ml[0][wv][l31] = m_i;
  ml[1][wv][l31] = l_i;
  __syncthreads();
  float m0 = ml[0][0][l31], m1 = ml[0][1][l31];
  float m2 = ml[0][2][l31], m3 = ml[0][3][l31];
  float mtot = fmaxf(fmaxf(m0, m1), fmaxf(m2, m3));
  float sw = __expf(m_i - mtot);  // idle wave: 0

  if (wv == 0) {
#pragma unroll
    for (int dt = 0; dt < 2; ++dt)
#pragma unroll
      for (int rg = 0; rg < 16; ++rg) {
        int d = dt * 32 + (rg & 3) + 8 * (rg >> 2) + 4 * half;
        Obuf[d][l31] = ot[dt][rg] * sw;
      }
  }
  __syncthreads();
#pragma unroll
  for (int w = 1; w < 4; ++w) {
    if (wv == w) {
#pragma unroll
      for (int dt = 0; dt < 2; ++dt)
#pragma unroll
        for (int rg = 0; rg < 16; ++rg) {
          int d = dt * 32 + (rg & 3) + 8 * (rg >> 2) + 4 * half;
          Obuf[d][l31] += ot[dt][rg] * sw;
        }
    }
    __syncthreads();
  }

  // ---- final normalize + coalesced store (128B per q-row) ---------------
  const int q = tid >> 3;            // 0..31
  const int d0 = (tid & 7) * 8;      // 0,8,..,56
  float mm0 = ml[0][0][q], mm1 = ml[0][1][q], mm2 = ml[0][2][q], mm3 = ml[0][3][q];
  float mt2 = fmaxf(fmaxf(mm0, mm1), fmaxf(mm2, mm3));
  float lt = ml[1][0][q] * __expf(mm0 - mt2) + ml[1][1][q] * __expf(mm1 - mt2) +
             ml[1][2][q] * __expf(mm2 - mt2) + ml[1][3][q] * __expf(mm3 - mt2);
  float inv = 1.0f / lt;  // lt >= 1
  unsigned u[4];
#pragma unroll
  for (int i = 0; i < 4; ++i) {
    float v0 = Obuf[d0 + 2 * i][q] * inv;
    float v1 = Obuf[d0 + 2 * i + 1][q] * inv;
    u[i] = (unsigned)(unsigned short)f2bf(v0) | ((unsigned)(unsigned short)f2bf(v1) << 16);
  }
  int4* dst = (int4*)(att + (size_t)(b * S_LEN + q0 + q) * D_MODEL + h * DHEAD + d0);
  *dst = make_int4(u[0], u[1], u[2], u[3]);
}

// ---------------------------------------------------------------------------
// Output projection: out = att (bf16) @ Wo^T (bf16) -> fp32. (unchanged)
// ---------------------------------------------------------------------------
__global__ __launch_bounds__(256) void out_gemm_kernel(
    const short* __restrict__ att, const short* __restrict__ Wob,
    float* __restrict__ out) {
  const int lane = threadIdx.x & 63;
  const int wave = threadIdx.x >> 6;
  const int col = lane & 15, quad = lane >> 4;
  const int tile = blockIdx.x * 4 + wave;
  const int tm = tile >> 4, tn = tile & 15;

  floatx4 acc[4][4];
#pragma unroll
  for (int i = 0; i < 4; ++i)
#pragma unroll
    for (int j = 0; j < 4; ++j) acc[i][j] = (floatx4){0.f, 0.f, 0.f, 0.f};

  const short* ap[4];
  const short* bp[4];
#pragma unroll
  for (int mt = 0; mt < 4; ++mt)
    ap[mt] = att + (size_t)(tm * 64 + mt * 16 + col) * D_MODEL + quad * 8;
#pragma unroll
  for (int nt = 0; nt < 4; ++nt)
    bp[nt] = Wob + (size_t)(tn * 64 + nt * 16 + col) * D_MODEL + quad * 8;

  for (int k0 = 0; k0 < D_MODEL; k0 += 32) {
    bf16x8 a[4], b[4];
#pragma unroll
    for (int mt = 0; mt < 4; ++mt) a[mt] = ld_frag(ap[mt] + k0);
#pragma unroll
    for (int nt = 0; nt < 4; ++nt) b[nt] = ld_frag(bp[nt] + k0);
#pragma unroll
    for (int mt = 0; mt < 4; ++mt)
#pragma unroll
      for (int nt = 0; nt < 4; ++nt)
        acc[mt][nt] = MFMA16(a[mt], b[nt], acc[mt][nt]);
  }

#pragma unroll
  for (int mt = 0; mt < 4; ++mt)
#pragma unroll
    for (int nt = 0; nt < 4; ++nt) {
      int n = tn * 64 + nt * 16 + col;
#pragma unroll
      for (int r = 0; r < 4; ++r) {
        int m = tm * 64 + mt * 16 + quad * 4 + r;
        out[(size_t)m * D_MODEL + n] = acc[mt][nt][r];
      }
    }
}

// ---------------------------------------------------------------------------
extern "C" void kernel_launch(void* const* d_in, const int* in_sizes, int n_in,
                              void* d_out, int out_size, void* d_ws, size_t ws_size,
                              hipStream_t stream) {
  const float* x  = (const float*)d_in[0];
  const float* Wq = (const float*)d_in[2];
  const float* Wk = (const float*)d_in[3];
  const float* Wv = (const float*)d_in[4];
  const float* Wo = (const float*)d_in[5];
  float* out = (float*)d_out;

  const size_t TENS = (size_t)NTOK * D_MODEL;
  const size_t WELEM = (size_t)D_MODEL * D_MODEL;

  short* qws  = (short*)d_out;
  short* xb   = (short*)d_out + TENS;
  short* kws  = (short*)d_ws;
  short* vtws = kws + TENS;
  short* attws = vtws + TENS;
  short* wqb = attws;
  short* wkb = wqb + WELEM;
  short* wvb = wkb + WELEM;
  float2* ropetab = (float2*)(wvb + WELEM);
  short* wob = kws;

  rope_tab_kernel<<<dim3(256), 256, 0, stream>>>(ropetab);
  cvt4_kernel<<<dim3(256, 4), 256, 0, stream>>>(x, Wq, Wk, Wv, xb, wqb, wkb, wvb);
  qkv_rope_kernel<<<dim3(256, 3), 256, 0, stream>>>(xb, wqb, wkb, wvb, ropetab, qws, kws, vtws);
  attn_kernel<<<dim3(2048), 256, 0, stream>>>(qws, kws, vtws, attws);
  cvt1_kernel<<<dim3(256), 256, 0, stream>>>(Wo, wob, (int)(WELEM >> 2));
  out_gemm_kernel<<<dim3(256), 256, 0, stream>>>(attws, wob, out);
}